// Round 3
// baseline (94.222 us; speedup 1.0000x reference)
//
#include <hip/hip_runtime.h>

// out[k] = sum_n sum_{i,j} frac[n,i]*frac[n,j]*cg[i,j,k]
//        = sum_{i,j} M[i][j] * cg[i,j,k],  M = sum_n x x^T (3x3 symmetric, 6 uniques)
//
// Single fused kernel:
//  - perfectly coalesced float4 loads (16B lane stride), reg->LDS scatter with
//    bank-swizzled padded slots, each lane reads back 4 contiguous rows.
//  - per-block partials -> agent-scope counter; last block reduces partials,
//    handles tail rows, contracts with cg, writes out[9].
// ws layout: ws[0..1] counter (zeroed by 4B memset node), partials at ws+2: [6][GRID].

constexpr int BLK  = 256;
constexpr int GRID = 2047;                  // 6*2047 partials + counter fits 48 KB ws
constexpr int ROWS_PER_BLOCK_ITER = 1024;   // 256 threads * 4 rows

// LDS slot: 12 data floats + pad. base = 14*t + 2*(t>>4) -> 64 lanes cover each
// bank pair exactly twice (2-way = free). Max = 14*63+6+12 = 900 < 912.
__device__ __forceinline__ int slot_base(int t) { return 14 * t + ((t >> 4) << 1); }

#define ACC6(x, y, z)                                              \
    do {                                                           \
        s00 = fmaf((x), (x), s00); s01 = fmaf((x), (y), s01);      \
        s02 = fmaf((x), (z), s02); s11 = fmaf((y), (y), s11);      \
        s12 = fmaf((y), (z), s12); s22 = fmaf((z), (z), s22);      \
    } while (0)

__global__ __launch_bounds__(BLK) void tp_fused(const float* __restrict__ frac,
                                                float* __restrict__ ws,
                                                const float* __restrict__ cg,
                                                float* __restrict__ out,
                                                int nrows, int iters) {
    __shared__ float lds[4][912];
    __shared__ float red[BLK / 64][6];
    __shared__ float fin[6 + 9];           // summed partials M6 + M9
    __shared__ int   is_last;

    const int lane = threadIdx.x & 63;
    const int w    = threadIdx.x >> 6;
    const float4* __restrict__ f4 = reinterpret_cast<const float4*>(frac);

    float s00 = 0.f, s01 = 0.f, s02 = 0.f, s11 = 0.f, s12 = 0.f, s22 = 0.f;

    for (int it = 0; it < iters; ++it) {
        // wave chunk: 192 float4 = 768 floats = 256 rows
        const long base = ((long)it * GRID + blockIdx.x) * 768L + w * 192;
        float4 v0 = f4[base + lane];
        float4 v1 = f4[base + 64 + lane];
        float4 v2 = f4[base + 128 + lane];

        // scatter: float4 r (r = 64m+lane) -> slot t=r/3, sub s=r%3
        #pragma unroll
        for (int m = 0; m < 3; ++m) {
            float4 v = (m == 0) ? v0 : (m == 1) ? v1 : v2;
            int r = 64 * m + lane;
            int t = r / 3;
            int a = slot_base(t) + 4 * (r - 3 * t);
            *reinterpret_cast<float2*>(&lds[w][a])     = make_float2(v.x, v.y);
            *reinterpret_cast<float2*>(&lds[w][a + 2]) = make_float2(v.z, v.w);
        }
        // gather own 4 rows (wave-private region; compiler inserts lgkmcnt)
        const int b0 = slot_base(lane);
        float2 q0 = *reinterpret_cast<const float2*>(&lds[w][b0]);
        float2 q1 = *reinterpret_cast<const float2*>(&lds[w][b0 + 2]);
        float2 q2 = *reinterpret_cast<const float2*>(&lds[w][b0 + 4]);
        float2 q3 = *reinterpret_cast<const float2*>(&lds[w][b0 + 6]);
        float2 q4 = *reinterpret_cast<const float2*>(&lds[w][b0 + 8]);
        float2 q5 = *reinterpret_cast<const float2*>(&lds[w][b0 + 10]);

        ACC6(q0.x, q0.y, q1.x);
        ACC6(q1.y, q2.x, q2.y);
        ACC6(q3.x, q3.y, q4.x);
        ACC6(q4.y, q5.x, q5.y);
    }

    // 64-lane butterfly reduction
    #pragma unroll
    for (int off = 32; off > 0; off >>= 1) {
        s00 += __shfl_down(s00, off);
        s01 += __shfl_down(s01, off);
        s02 += __shfl_down(s02, off);
        s11 += __shfl_down(s11, off);
        s12 += __shfl_down(s12, off);
        s22 += __shfl_down(s22, off);
    }
    if (lane == 0) {
        red[w][0] = s00; red[w][1] = s01; red[w][2] = s02;
        red[w][3] = s11; red[w][4] = s12; red[w][5] = s22;
    }
    __syncthreads();

    // thread 0 publishes partials + counter (release RMW orders prior stores)
    if (threadIdx.x == 0) {
        #pragma unroll
        for (int c = 0; c < 6; ++c) {
            float v = red[0][c] + red[1][c] + red[2][c] + red[3][c];
            ws[2 + c * GRID + blockIdx.x] = v;
        }
        unsigned old = __hip_atomic_fetch_add(reinterpret_cast<unsigned*>(ws), 1u,
                                              __ATOMIC_ACQ_REL, __HIP_MEMORY_SCOPE_AGENT);
        is_last = (old == GRID - 1) ? 1 : 0;
    }
    __syncthreads();
    if (!is_last) return;

    // ---- last block: final reduction + tail + contraction ----
    float s[6] = {0.f, 0.f, 0.f, 0.f, 0.f, 0.f};
    for (int b = threadIdx.x; b < GRID; b += BLK) {
        #pragma unroll
        for (int c = 0; c < 6; ++c)
            s[c] += __hip_atomic_load(&ws[2 + c * GRID + b],
                                      __ATOMIC_RELAXED, __HIP_MEMORY_SCOPE_AGENT);
    }
    // tail rows not covered by the main loop (0 for N=2^23)
    const long done = (long)iters * GRID * ROWS_PER_BLOCK_ITER;
    for (long r = done + threadIdx.x; r < nrows; r += BLK) {
        float x = frac[3 * r + 0], y = frac[3 * r + 1], z = frac[3 * r + 2];
        s[0] = fmaf(x, x, s[0]); s[1] = fmaf(x, y, s[1]); s[2] = fmaf(x, z, s[2]);
        s[3] = fmaf(y, y, s[3]); s[4] = fmaf(y, z, s[4]); s[5] = fmaf(z, z, s[5]);
    }

    #pragma unroll
    for (int off = 32; off > 0; off >>= 1) {
        #pragma unroll
        for (int c = 0; c < 6; ++c) s[c] += __shfl_down(s[c], off);
    }
    if (lane == 0) {
        #pragma unroll
        for (int c = 0; c < 6; ++c) red[w][c] = s[c];
    }
    __syncthreads();
    if (threadIdx.x < 6)
        fin[threadIdx.x] = red[0][threadIdx.x] + red[1][threadIdx.x]
                         + red[2][threadIdx.x] + red[3][threadIdx.x];
    __syncthreads();
    if (threadIdx.x == 0) {
        fin[6 + 0] = fin[0]; fin[6 + 1] = fin[1]; fin[6 + 2] = fin[2];
        fin[6 + 3] = fin[1]; fin[6 + 4] = fin[3]; fin[6 + 5] = fin[4];
        fin[6 + 6] = fin[2]; fin[6 + 7] = fin[4]; fin[6 + 8] = fin[5];
    }
    __syncthreads();
    if (threadIdx.x < 9) {
        const int k = threadIdx.x;
        float acc = 0.f;
        #pragma unroll
        for (int p = 0; p < 9; ++p)
            acc = fmaf(fin[6 + p], cg[p * 9 + k], acc);   // cg[(i*3+j)*9 + k]
        out[k] = acc;
    }
}

extern "C" void kernel_launch(void* const* d_in, const int* in_sizes, int n_in,
                              void* d_out, int out_size, void* d_ws, size_t ws_size,
                              hipStream_t stream) {
    const float* frac = (const float*)d_in[0];   // [N, 3] flat
    const float* cg   = (const float*)d_in[1];   // [3, 3, 9] flat
    float*       out  = (float*)d_out;           // [9]
    float*       ws   = (float*)d_ws;            // counter + 6*GRID partials < 48 KB

    const int nrows = in_sizes[0] / 3;
    const int iters = nrows / (GRID * ROWS_PER_BLOCK_ITER);  // tail done by last block

    hipMemsetAsync(d_ws, 0, 4, stream);          // zero arrival counter (poison-safe)
    tp_fused<<<GRID, BLK, 0, stream>>>(frac, ws, cg, out, nrows, iters);
}

// Round 4
// 25.803 us; speedup vs baseline: 3.6516x; 3.6516x over previous
//
#include <hip/hip_runtime.h>

// out[k] = sum_n sum_{i,j} frac[n,i]*frac[n,j]*cg[i,j,k]
//        = sum_{i,j} M[i][j] * cg[i,j,k],  M = sum_n x x^T (3x3 symmetric, 6 uniques)
//
// Pass 1: perfectly coalesced (16B lane stride) float4 loads + overlapping 8B
//   float2 (L1-served, same lines as neighbor lane's float4). Phase-relative
//   accumulation: with GRID*BLK % 3 == 0, lane phase p = tid%3 is loop-invariant,
//   so the 12-FMA body is branchless; one 3-way map after the loop.
// Pass 2: 1 block, coalesced float4 reads of padded transposed partials, cg contract.
//
// Requires N % 4 == 0 (harness N = 2^23). No cross-block coherence games
// (round-3 post-mortem: agent-scope release per block = L2 writeback x GRID = 131us).

constexpr int BLK  = 256;
constexpr int GRID = 2046;   // divisible by 3 (phase invariance); ~8 blocks/CU
constexpr int PG   = 2048;   // padded partial stride (float4-friendly)

__global__ __launch_bounds__(BLK) void tp_partial(const float* __restrict__ frac,
                                                  float* __restrict__ ws,
                                                  int nq) {  // nq = 3N/4 float4s
    const float4* __restrict__ f4 = reinterpret_cast<const float4*>(frac);
    const int tid    = blockIdx.x * BLK + threadIdx.x;
    const int stride = GRID * BLK;              // % 3 == 0 -> phase invariant

    // phase-relative buckets: squares r[3], pairs pr[3], skips sk[3]
    float r0 = 0.f, r1 = 0.f, r2 = 0.f;
    float p0 = 0.f, p1 = 0.f, p2 = 0.f;
    float k0 = 0.f, k1 = 0.f, k2 = 0.f;

    const int full = nq / stride;               // uniform trip count
    int g = tid;
    #pragma unroll 2
    for (int it = 0; it <= full; ++it, g += stride) {
        if (it == full && g >= nq) break;       // remainder guard
        float4 v = f4[g];
        float2 e;
        if (g == nq - 1) e = make_float2(0.f, 0.f);   // OOB guard: only feeds
        else e = *reinterpret_cast<const float2*>(&frac[4 * g + 4]); // discarded buckets
        const float h0 = v.x, h1 = v.y, h2 = v.z, h3 = v.w, h4 = e.x, h5 = e.y;
        r0 = fmaf(h0, h0, r0); r0 = fmaf(h3, h3, r0);
        r1 = fmaf(h1, h1, r1);
        r2 = fmaf(h2, h2, r2);
        p0 = fmaf(h0, h1, p0); p0 = fmaf(h3, h4, p0);
        p1 = fmaf(h1, h2, p1);
        p2 = fmaf(h2, h3, p2);
        k0 = fmaf(h0, h2, k0); k0 = fmaf(h3, h5, k0);
        k1 = fmaf(h1, h3, k1);
        k2 = fmaf(h2, h4, k2);
    }

    // map phase-relative buckets -> global (verified by hand for p=0,1,2)
    float s00, s01, s02, s11, s12, s22;
    const int ph = tid % 3;
    if (ph == 0)      { s00 = r0; s11 = r1; s22 = r2; s01 = p0; s12 = p1; s02 = k0; }
    else if (ph == 1) { s11 = r0; s22 = r1; s00 = r2; s12 = p0; s01 = p2; s02 = k2; }
    else              { s22 = r0; s00 = r1; s11 = r2; s01 = p1; s12 = p2; s02 = k1; }

    // 64-lane butterfly reduction
    #pragma unroll
    for (int off = 32; off > 0; off >>= 1) {
        s00 += __shfl_down(s00, off);
        s01 += __shfl_down(s01, off);
        s02 += __shfl_down(s02, off);
        s11 += __shfl_down(s11, off);
        s12 += __shfl_down(s12, off);
        s22 += __shfl_down(s22, off);
    }

    __shared__ float red[BLK / 64][6];
    const int lane = threadIdx.x & 63;
    const int wave = threadIdx.x >> 6;
    if (lane == 0) {
        red[wave][0] = s00; red[wave][1] = s01; red[wave][2] = s02;
        red[wave][3] = s11; red[wave][4] = s12; red[wave][5] = s22;
    }
    __syncthreads();
    if (threadIdx.x < 6) {
        float v = red[0][threadIdx.x] + red[1][threadIdx.x]
                + red[2][threadIdx.x] + red[3][threadIdx.x];
        ws[threadIdx.x * PG + blockIdx.x] = v;   // transposed, padded
    }
    // zero the pad slots (GRID..PG-1) so pass-2 float4 reads are clean
    if (blockIdx.x < PG - GRID && threadIdx.x < 6)
        ws[threadIdx.x * PG + GRID + blockIdx.x] = 0.f;
}

__global__ __launch_bounds__(BLK) void tp_final(const float* __restrict__ ws,
                                                const float* __restrict__ cg,
                                                float* __restrict__ out) {
    const float4* __restrict__ w4 = reinterpret_cast<const float4*>(ws); // [6][PG/4]
    constexpr int Q = PG / 4;   // 512 float4 per component

    float s[6];
    #pragma unroll
    for (int c = 0; c < 6; ++c) {
        float4 a = w4[c * Q + threadIdx.x];
        float4 b = w4[c * Q + threadIdx.x + BLK];
        s[c] = ((a.x + a.y) + (a.z + a.w)) + ((b.x + b.y) + (b.z + b.w));
    }

    #pragma unroll
    for (int off = 32; off > 0; off >>= 1) {
        #pragma unroll
        for (int c = 0; c < 6; ++c) s[c] += __shfl_down(s[c], off);
    }

    __shared__ float red[BLK / 64][6];
    const int lane = threadIdx.x & 63;
    const int wave = threadIdx.x >> 6;
    if (lane == 0) {
        #pragma unroll
        for (int c = 0; c < 6; ++c) red[wave][c] = s[c];
    }
    __syncthreads();

    __shared__ float M[9];
    if (threadIdx.x == 0) {
        float t[6];
        #pragma unroll
        for (int c = 0; c < 6; ++c)
            t[c] = red[0][c] + red[1][c] + red[2][c] + red[3][c];
        M[0] = t[0];  M[1] = t[1];  M[2] = t[2];
        M[3] = t[1];  M[4] = t[3];  M[5] = t[4];
        M[6] = t[2];  M[7] = t[4];  M[8] = t[5];
    }
    __syncthreads();

    if (threadIdx.x < 9) {
        const int k = threadIdx.x;
        float acc = 0.f;
        #pragma unroll
        for (int p = 0; p < 9; ++p)
            acc = fmaf(M[p], cg[p * 9 + k], acc);   // cg[(i*3+j)*9 + k]
        out[k] = acc;
    }
}

extern "C" void kernel_launch(void* const* d_in, const int* in_sizes, int n_in,
                              void* d_out, int out_size, void* d_ws, size_t ws_size,
                              hipStream_t stream) {
    const float* frac = (const float*)d_in[0];   // [N, 3] flat
    const float* cg   = (const float*)d_in[1];   // [3, 3, 9] flat
    float*       out  = (float*)d_out;           // [9]
    float*       ws   = (float*)d_ws;            // 6*PG floats = 48 KB

    const int nfloats = in_sizes[0];             // 3N, divisible by 4
    const int nq      = nfloats >> 2;            // float4 count

    tp_partial<<<GRID, BLK, 0, stream>>>(frac, ws, nq);
    tp_final<<<1, BLK, 0, stream>>>(ws, cg, out);
}

// Round 5
// 22.943 us; speedup vs baseline: 4.1068x; 1.1247x over previous
//
#include <hip/hip_runtime.h>

// out[k] = sum_n sum_{i,j} frac[n,i]*frac[n,j]*cg[i,j,k]
//        = sum_{i,j} M[i][j] * cg[i,j,k],  M = sum_n x x^T (3x3 symmetric, 6 uniques)
//
// Pass 1: each wave owns one contiguous 3 KB chunk (768 float4 = 1024 rows).
//   Lane owns 48 B = 3 consecutive float4 = 4 COMPLETE rows (no straddle),
//   4 segments x 3 loads = 12 dwordx4 issued straight-line (12-deep MLP,
//   zero branches, 48-line/KB TA footprint = half of R2's 96B-stride).
// Pass 2: 1 block, coalesced float4 reads of transposed partials + generic
//   row tail + cg contraction.
//
// R3 post-mortem: no cross-block coherence (agent-scope release per block
// = per-block L2 writeback = 131 us). Two stream-ordered kernels.

constexpr int BLK  = 256;
constexpr int GRID = 2048;
constexpr int WPB  = BLK / 64;              // 4 waves per block
constexpr long NWAVES = (long)GRID * WPB;   // 8192
// chunk = 768 float4 = 3072 floats = 1024 rows

#define ACC6(x, y, z)                                              \
    do {                                                           \
        s00 = fmaf((x), (x), s00); s01 = fmaf((x), (y), s01);      \
        s02 = fmaf((x), (z), s02); s11 = fmaf((y), (y), s11);      \
        s12 = fmaf((y), (z), s12); s22 = fmaf((z), (z), s22);      \
    } while (0)

__global__ __launch_bounds__(BLK) void tp_partial(const float* __restrict__ frac,
                                                  float* __restrict__ ws,
                                                  long nchunks) {
    const int  lane = threadIdx.x & 63;
    const int  w    = threadIdx.x >> 6;
    const long wglb = (long)blockIdx.x * WPB + w;
    const float4* __restrict__ f4 = reinterpret_cast<const float4*>(frac);

    float s00 = 0.f, s01 = 0.f, s02 = 0.f, s11 = 0.f, s12 = 0.f, s22 = 0.f;

    for (long c = wglb; c < nchunks; c += NWAVES) {   // trip count 1 for N=2^23
        const long base = c * 768 + lane * 3;         // float index 4*base % 3 == 0
        float4 v[12];
        #pragma unroll
        for (int s = 0; s < 4; ++s)
            #pragma unroll
            for (int k = 0; k < 3; ++k)
                v[s * 3 + k] = f4[base + 192 * s + k];   // all 12 loads in flight

        #pragma unroll
        for (int s = 0; s < 4; ++s) {
            const float4 a = v[s * 3 + 0];
            const float4 b = v[s * 3 + 1];
            const float4 d = v[s * 3 + 2];
            ACC6(a.x, a.y, a.z);
            ACC6(a.w, b.x, b.y);
            ACC6(b.z, b.w, d.x);
            ACC6(d.y, d.z, d.w);
        }
    }

    // 64-lane butterfly reduction
    #pragma unroll
    for (int off = 32; off > 0; off >>= 1) {
        s00 += __shfl_down(s00, off);
        s01 += __shfl_down(s01, off);
        s02 += __shfl_down(s02, off);
        s11 += __shfl_down(s11, off);
        s12 += __shfl_down(s12, off);
        s22 += __shfl_down(s22, off);
    }

    __shared__ float red[WPB][6];
    if (lane == 0) {
        red[w][0] = s00; red[w][1] = s01; red[w][2] = s02;
        red[w][3] = s11; red[w][4] = s12; red[w][5] = s22;
    }
    __syncthreads();
    if (threadIdx.x < 6) {
        float v = red[0][threadIdx.x] + red[1][threadIdx.x]
                + red[2][threadIdx.x] + red[3][threadIdx.x];
        ws[threadIdx.x * GRID + blockIdx.x] = v;   // transposed [6][GRID]
    }
}

__global__ __launch_bounds__(BLK) void tp_final(const float* __restrict__ frac,
                                                const float* __restrict__ ws,
                                                const float* __restrict__ cg,
                                                float* __restrict__ out,
                                                long tail_row, long nrows) {
    const float4* __restrict__ w4 = reinterpret_cast<const float4*>(ws); // [6][GRID/4]
    constexpr int Q = GRID / 4;   // 512 float4 per component

    float s[6];
    #pragma unroll
    for (int c = 0; c < 6; ++c) {
        float4 a = w4[c * Q + threadIdx.x];
        float4 b = w4[c * Q + threadIdx.x + BLK];
        s[c] = ((a.x + a.y) + (a.z + a.w)) + ((b.x + b.y) + (b.z + b.w));
    }

    // generic row tail (none for N = 2^23)
    for (long r = tail_row + threadIdx.x; r < nrows; r += BLK) {
        float x = frac[3 * r + 0], y = frac[3 * r + 1], z = frac[3 * r + 2];
        s[0] = fmaf(x, x, s[0]); s[1] = fmaf(x, y, s[1]); s[2] = fmaf(x, z, s[2]);
        s[3] = fmaf(y, y, s[3]); s[4] = fmaf(y, z, s[4]); s[5] = fmaf(z, z, s[5]);
    }

    #pragma unroll
    for (int off = 32; off > 0; off >>= 1) {
        #pragma unroll
        for (int c = 0; c < 6; ++c) s[c] += __shfl_down(s[c], off);
    }

    __shared__ float red[BLK / 64][6];
    const int lane = threadIdx.x & 63;
    const int wave = threadIdx.x >> 6;
    if (lane == 0) {
        #pragma unroll
        for (int c = 0; c < 6; ++c) red[wave][c] = s[c];
    }
    __syncthreads();

    __shared__ float M[9];
    if (threadIdx.x == 0) {
        float t[6];
        #pragma unroll
        for (int c = 0; c < 6; ++c)
            t[c] = red[0][c] + red[1][c] + red[2][c] + red[3][c];
        M[0] = t[0];  M[1] = t[1];  M[2] = t[2];
        M[3] = t[1];  M[4] = t[3];  M[5] = t[4];
        M[6] = t[2];  M[7] = t[4];  M[8] = t[5];
    }
    __syncthreads();

    if (threadIdx.x < 9) {
        const int k = threadIdx.x;
        float acc = 0.f;
        #pragma unroll
        for (int p = 0; p < 9; ++p)
            acc = fmaf(M[p], cg[p * 9 + k], acc);   // cg[(i*3+j)*9 + k]
        out[k] = acc;
    }
}

extern "C" void kernel_launch(void* const* d_in, const int* in_sizes, int n_in,
                              void* d_out, int out_size, void* d_ws, size_t ws_size,
                              hipStream_t stream) {
    const float* frac = (const float*)d_in[0];   // [N, 3] flat
    const float* cg   = (const float*)d_in[1];   // [3, 3, 9] flat
    float*       out  = (float*)d_out;           // [9]
    float*       ws   = (float*)d_ws;            // 6*GRID floats = 48 KB

    const long nfloats  = in_sizes[0];           // 3*N
    const long nrows    = nfloats / 3;
    const long nchunks  = nfloats / 3072;        // 3 KB chunks (exact: 8192)
    const long tail_row = nchunks * 1024;        // rows covered by pass 1

    tp_partial<<<GRID, BLK, 0, stream>>>(frac, ws, nchunks);
    tp_final<<<1, BLK, 0, stream>>>(frac, ws, cg, out, tail_row, nrows);
}